// Round 11
// baseline (133.123 us; speedup 1.0000x reference)
//
#include <hip/hip_runtime.h>

typedef __attribute__((ext_vector_type(8))) short short8;
typedef __attribute__((ext_vector_type(4))) float f32x4;
typedef unsigned short u16;

// ---------------- helpers ----------------
__device__ __forceinline__ u16 f2bf(float f){
  unsigned int u = __float_as_uint(f);
  u += 0x7FFFu + ((u>>16)&1u);
  return (u16)(u>>16);
}
__device__ __forceinline__ float bf2f(u16 h){
  return __uint_as_float(((unsigned int)h)<<16);
}
__device__ __forceinline__ float sigm(float x){ return 1.f/(1.f+__expf(-x)); }

// raw v_exp_f32 (base-2); exp2f() goes through OCML fixup code.
__device__ __forceinline__ float fexp2(float x){
#if __has_builtin(__builtin_amdgcn_exp2f)
  return __builtin_amdgcn_exp2f(x);
#else
  float r; asm("v_exp_f32 %0, %1" : "=v"(r) : "v"(x)); return r;
#endif
}

// async global->LDS, 16B per lane. LDS dest = wave-uniform base + lane*16.
__device__ __forceinline__ void gl_lds(const u16* g, u16* l){
  __builtin_amdgcn_global_load_lds(
      (const __attribute__((address_space(1))) void*)g,
      (__attribute__((address_space(3))) void*)l, 16, 0, 0);
}

#define MDIM 2048
#define DDIM 1024
#define KDIM 1024
#define LOG2E 1.44269504f
#define NCHUNK 32   // chunks per sequence
#define TCH 32      // timesteps per chunk

// ---------------- weight conversion (f32 -> bf16) ----------------
// concat segments (element offsets): selW 1048576 | Wx 196608 | gateW 1048576 |
// impW 65536 | Wout 1048576 | dtW 65536  (total 3473664)
__global__ __launch_bounds__(256) void convert_k(
    const float* __restrict__ selW, const float* __restrict__ Wx,
    const float* __restrict__ gateW, const float* __restrict__ impW,
    const float* __restrict__ Wout, const float* __restrict__ dtW,
    u16* __restrict__ dA, u16* __restrict__ dB, u16* __restrict__ dC,
    u16* __restrict__ dD)
{
  int e = (blockIdx.x*256 + threadIdx.x)*4;
  if (e >= 3473664) return;
  const float4* s; u16* d;
  if (e < 1048576){ s=(const float4*)(selW+e); d=dA+e; }
  else if (e < 1245184){ int o=e-1048576; s=(const float4*)(Wx+o); d=dA+1048576+o; }
  else if (e < 2293760){ int o=e-1245184; s=(const float4*)(gateW+o); d=dB+o; }
  else if (e < 2359296){ int o=e-2293760; s=(const float4*)(impW+o); d=dB+1048576+o; }
  else if (e < 3407872){ int o=e-2359296; s=(const float4*)(Wout+o); d=dC+o; }
  else { int o=e-3407872; s=(const float4*)(dtW+o); d=dD+o; }
  float4 v = *s;
  ushort4 ov; ov.x=f2bf(v.x); ov.y=f2bf(v.y); ov.z=f2bf(v.z); ov.w=f2bf(v.w);
  *(ushort4*)d = ov;
}

// ---------------- RMSNorm ----------------
__global__ __launch_bounds__(256) void rmsnorm_k(
    const float* __restrict__ x, const float* __restrict__ w, u16* __restrict__ xn)
{
  int row = blockIdx.x, tid = threadIdx.x;
  float4 xv = ((const float4*)(x + (size_t)row*DDIM))[tid];
  float s = xv.x*xv.x + xv.y*xv.y + xv.z*xv.z + xv.w*xv.w;
  #pragma unroll
  for (int m=1; m<64; m<<=1) s += __shfl_xor(s, m);
  __shared__ float red[4];
  if ((tid&63)==0) red[tid>>6] = s;
  __syncthreads();
  float tot = red[0]+red[1]+red[2]+red[3];
  float rs = rsqrtf(tot*(1.f/1024.f) + 1e-6f);
  float4 wv = ((const float4*)w)[tid];
  ushort4 o;
  o.x=f2bf(xv.x*rs*wv.x); o.y=f2bf(xv.y*rs*wv.y);
  o.z=f2bf(xv.z*rs*wv.z); o.w=f2bf(xv.w*rs*wv.w);
  ((ushort4*)(xn + (size_t)row*DDIM))[tid] = o;
}

// ---------------- MFMA GEMM: C[m,n] = sum_k X[m,k]*W[n,k], K=1024 ----------------
// Tile 64x64, BK=128 (8 iters), dbuf + raw s_barrier + counted vmcnt(8).
// 16 MFMA/wave/iter. T2 swizzle: LDS row stride 256B; slot bits 3-5 XOR (row&7),
// source pre-swizzled with the same involution. T1 XCD swizzle (nwg%8==0).
// MODE 0: W=[selW|Wx] N=1216 -> xn2(bf16), delta_r(bf16), BC(f32)
// MODE 1: W=[gateW|impW] N=1088 -> xn3(bf16), BI=B*imp, CI=C*imp (f32)
// MODE 2: W=Wout N=1024 -> out(f32)
template<int MODE>
__global__ __launch_bounds__(256) void gemm_bt(
    const u16* __restrict__ X, const u16* __restrict__ W,
    const float* __restrict__ b1, const float* __restrict__ b2,
    const float* __restrict__ b3, const u16* __restrict__ aux,
    u16* __restrict__ oBF, u16* __restrict__ oBF2,
    float* __restrict__ oF1, float* __restrict__ oF2, float* __restrict__ oF3)
{
  __shared__ __align__(16) u16 As[2][64*128];   // [row][k] row stride 128 u16 = 256B
  __shared__ __align__(16) u16 Bs[2][64*128];
  const int tid = threadIdx.x;
  const int wid = tid>>6, lane = tid&63;
  const int wr = wid>>1, wc = wid&1;
  const int lr = lane&15, lg = lane>>4;

  // T1: XCD-contiguous logical tiles
  const int nx = gridDim.x;
  const int nwg = nx*gridDim.y;
  const int lin = blockIdx.y*nx + blockIdx.x;
  const int lt = (lin&7)*(nwg>>3) + (lin>>3);
  const int bm = (lt/nx)*64, bn = (lt%nx)*64;

  f32x4 acc[2][2];
  #pragma unroll
  for (int a0=0;a0<2;++a0)
    #pragma unroll
    for (int b0=0;b0<2;++b0) acc[a0][b0] = (f32x4){0.f,0.f,0.f,0.f};

  // staging map: one gl_lds call covers 16 rows x 128 u16 (2048 u16/block).
  // thread t: row srow = t>>4, u16 col = 8*(t&15) XOR ((srow&7)<<3)  (T2 source
  // pre-swizzle; LDS dest stays linear).
  const int srow = tid>>4;
  const int scol = (8*(tid&15)) ^ ((srow&7)<<3);
  const u16* ag = X + (size_t)(bm + srow)*KDIM + scol;
  const u16* bg = W + (size_t)(bn + srow)*KDIM + scol;
  const int lofs = wid*512;                      // u16 (wave chunk within 2048)

  // 8 gl_lds per wave per tile -> vmcnt(8) == "my previous tile has landed"
  auto stage = [&](int buf, int kt){
    #pragma unroll
    for (int j=0;j<4;++j){
      gl_lds(ag + (size_t)(j*16)*KDIM + kt, As[buf] + j*2048 + lofs);
      gl_lds(bg + (size_t)(j*16)*KDIM + kt, Bs[buf] + j*2048 + lofs);
    }
  };

  stage(0, 0);
  stage(1, 128);
  asm volatile("s_waitcnt vmcnt(8)" ::: "memory");
  __builtin_amdgcn_s_barrier();

  int cur = 0;
  #pragma unroll
  for (int t=0; t<8; ++t){
    short8 af[2][4], bfr[2][4];
    #pragma unroll
    for (int a0=0;a0<2;++a0){
      const int R = wr*32 + a0*16 + lr;
      #pragma unroll
      for (int kh=0;kh<4;++kh)
        af[a0][kh] = *(const short8*)(As[cur] + R*128 + ((kh*32 + lg*8) ^ ((lr&7)<<3)));
    }
    #pragma unroll
    for (int b0=0;b0<2;++b0){
      const int R = wc*32 + b0*16 + lr;
      #pragma unroll
      for (int kh=0;kh<4;++kh)
        bfr[b0][kh] = *(const short8*)(Bs[cur] + R*128 + ((kh*32 + lg*8) ^ ((lr&7)<<3)));
    }
    asm volatile("s_waitcnt lgkmcnt(0)" ::: "memory");
    __builtin_amdgcn_sched_barrier(0);
    __builtin_amdgcn_s_barrier();
    if (t < 6)
      stage(cur, (t+2)*128);           // overwrite buf[cur] with tile t+2
    #pragma unroll
    for (int kh=0;kh<4;++kh)
      #pragma unroll
      for (int a0=0;a0<2;++a0)
        #pragma unroll
        for (int b0=0;b0<2;++b0)
          acc[a0][b0] = __builtin_amdgcn_mfma_f32_16x16x32_bf16(af[a0][kh], bfr[b0][kh], acc[a0][b0], 0, 0, 0);
    __builtin_amdgcn_sched_barrier(0);  // keep MFMA above the wait
    if (t < 6){
      asm volatile("s_waitcnt vmcnt(8)" ::: "memory");  // tile t+1 landed; t+2 in flight
      __builtin_amdgcn_s_barrier();
    } else if (t == 6){
      asm volatile("s_waitcnt vmcnt(0)" ::: "memory");  // last prefetched tile
      __builtin_amdgcn_s_barrier();
    }
    cur ^= 1;
  }

  const int colb = bn + wc*32;
  #pragma unroll
  for (int a0=0;a0<2;++a0){
    const int m0 = bm + wr*32 + a0*16 + lg*4;
    #pragma unroll
    for (int b0=0;b0<2;++b0){
      const int n = colb + b0*16 + lr;
      #pragma unroll
      for (int i=0;i<4;++i){
        const int m = m0 + i;
        float v = acc[a0][b0][i];
        if constexpr (MODE==0){
          if (n < 1024){
            float s = sigm((v + b1[n])*b2[n]);
            float xnv = bf2f(aux[(size_t)m*1024 + n]);
            oBF[(size_t)m*1024 + n] = f2bf(xnv*s);
          } else if (n < 1088){
            oBF2[(size_t)m*64 + (n-1024)] = f2bf(v);        // delta_r
          } else {
            oF2[(size_t)m*128 + (n-1088)] = v;              // B,C
          }
        } else if constexpr (MODE==1){
          if (n < 1024){
            float g = sigm(v + b1[n]);
            oBF[(size_t)m*1024 + n] = f2bf(bf2f(aux[(size_t)m*1024 + n])*g);  // xn3 bf16
          } else {
            int c = n-1024;
            float it = sigm(v + b2[c]);
            float bb = b3[(size_t)m*128 + c];
            float cc = b3[(size_t)m*128 + 64 + c];
            oF2[(size_t)m*64 + c] = bb*it;   // BI = B*imp
            oF3[(size_t)m*64 + c] = cc*it;   // CI = C*imp
          }
        } else {
          oF1[(size_t)m*1024 + n] = v;
        }
      }
    }
  }
}

// ---------------- delta_k: delta[m,d] = softplus(sum_r dr[m,r]*dtW[d,r] + dtb[d]) ----------------
// K=64, single MFMA pass. Tile 64x64, 4 waves 2x2 (BK=64 swizzle scheme).
__global__ __launch_bounds__(256) void delta_k(
    const u16* __restrict__ dr, const u16* __restrict__ dtWb,
    const float* __restrict__ dtb, u16* __restrict__ delta16)
{
  __shared__ __align__(16) u16 As[64*64];
  __shared__ __align__(16) u16 Bs[64*64];
  const int tid = threadIdx.x;
  const int wid = tid>>6, lane = tid&63;
  const int wr = wid>>1, wc = wid&1;
  const int lr = lane&15, lg = lane>>4;
  const int bm = blockIdx.y*64, bn = blockIdx.x*64;

  const int srow = wid*8 + (lane>>3);
  const int kslot = 8*((lane&7) ^ (lane>>3));
  const u16* ag = dr   + (size_t)(bm + srow)*64 + kslot;
  const u16* bg = dtWb + (size_t)(bn + srow)*64 + kslot;
  const int lofs = wid*512;

  gl_lds(ag, As + lofs);
  gl_lds(ag + 32*64, As + 2048 + lofs);
  gl_lds(bg, Bs + lofs);
  gl_lds(bg + 32*64, Bs + 2048 + lofs);
  asm volatile("s_waitcnt vmcnt(0)" ::: "memory");
  __builtin_amdgcn_s_barrier();

  f32x4 acc[2][2];
  #pragma unroll
  for (int a0=0;a0<2;++a0)
    #pragma unroll
    for (int b0=0;b0<2;++b0) acc[a0][b0] = (f32x4){0.f,0.f,0.f,0.f};

  short8 af[2][2], bfr[2][2];
  #pragma unroll
  for (int a0=0;a0<2;++a0){
    const int R = wr*32 + a0*16 + lr;
    #pragma unroll
    for (int kh=0;kh<2;++kh)
      af[a0][kh] = *(const short8*)(As + R*64 + ((kh*32 + lg*8) ^ ((lr&7)<<3)));
  }
  #pragma unroll
  for (int b0=0;b0<2;++b0){
    const int R = wc*32 + b0*16 + lr;
    #pragma unroll
    for (int kh=0;kh<2;++kh)
      bfr[b0][kh] = *(const short8*)(Bs + R*64 + ((kh*32 + lg*8) ^ ((lr&7)<<3)));
  }
  #pragma unroll
  for (int kh=0;kh<2;++kh)
    #pragma unroll
    for (int a0=0;a0<2;++a0)
      #pragma unroll
      for (int b0=0;b0<2;++b0)
        acc[a0][b0] = __builtin_amdgcn_mfma_f32_16x16x32_bf16(af[a0][kh], bfr[b0][kh], acc[a0][b0], 0, 0, 0);

  #pragma unroll
  for (int a0=0;a0<2;++a0){
    const int m0 = bm + wr*32 + a0*16 + lg*4;
    #pragma unroll
    for (int b0=0;b0<2;++b0){
      const int n = bn + wc*32 + b0*16 + lr;
      const float bias = dtb[n];
      #pragma unroll
      for (int i=0;i<4;++i){
        float t = acc[a0][b0][i] + bias;
        float sp = fmaxf(t,0.f) + log1pf(__expf(-fabsf(t)));
        delta16[(size_t)(m0+i)*1024 + n] = f2bf(sp);
      }
    }
  }
}

// ---------------- chunked selective scan (bf16 delta/xn3 inputs) ----------------
// 32 chunks x 32 steps; block = 256 threads = 4 waves; wave wv owns n-states
// [wv*16, wv*16+16); lane = d. hst is bf16: [c*2+b][n][d].
__global__ __launch_bounds__(256) void scan_p1(
    const u16* __restrict__ delta, const u16* __restrict__ xn3,
    const float* __restrict__ BI, const float* __restrict__ A_log,
    u16* __restrict__ hst, float* __restrict__ sumdt)
{
  const int tid = threadIdx.x;
  const int lane = tid & 63;
  const int wv = __builtin_amdgcn_readfirstlane(tid >> 6);
  const int dg = blockIdx.x, c = blockIdx.y, b = blockIdx.z;
  const int d = dg*64 + lane;
  const int nb = wv*16;
  float A2[16], h[16];
  #pragma unroll
  for (int n0=0;n0<4;++n0){
    float4 al = *(const float4*)(A_log + (size_t)d*64 + nb + n0*4);
    A2[n0*4+0] = -__expf(al.x)*LOG2E;
    A2[n0*4+1] = -__expf(al.y)*LOG2E;
    A2[n0*4+2] = -__expf(al.z)*LOG2E;
    A2[n0*4+3] = -__expf(al.w)*LOG2E;
  }
  #pragma unroll
  for (int n=0;n<16;++n) h[n]=0.f;
  const int row0 = b*1024 + c*TCH;
  float sdt = 0.f;
  for (int t=0;t<TCH;++t){
    const size_t row = row0 + t;
    float dt = bf2f(delta[row*1024 + d]);
    float xt = bf2f(xn3[row*1024 + d]);
    sdt += dt;
    float k = dt*xt;
    const float* bi = BI + row*64 + nb;   // wave-uniform -> s_loads
    #pragma unroll
    for (int n=0;n<16;++n)
      h[n] = fexp2(dt*A2[n])*h[n] + k*bi[n];
  }
  if (wv==0) sumdt[(size_t)(c*2+b)*1024 + d] = sdt;
  #pragma unroll
  for (int n=0;n<16;++n)
    hst[(size_t)((c*2+b)*64 + nb + n)*1024 + d] = f2bf(h[n]);
}

// phase 2: sequential prefix over 32 chunks, in-place: hst[c] <- h_start of chunk c
__global__ __launch_bounds__(256) void scan_p2(
    const float* __restrict__ A_log, const float* __restrict__ sumdt,
    u16* __restrict__ hst)
{
  int gid = blockIdx.x*256 + threadIdx.x;   // 512 blocks -> 131072 threads
  int d = gid & 1023, n = (gid>>10)&63, b = gid>>16;
  float A2 = -__expf(A_log[(size_t)d*64 + n])*LOG2E;
  float carry = 0.f;
  #pragma unroll
  for (int c=0;c<NCHUNK;++c){
    float P = fexp2(A2 * sumdt[(size_t)(c*2+b)*1024 + d]);
    size_t off = (size_t)((c*2+b)*64 + n)*1024 + d;
    float he = bf2f(hst[off]);
    hst[off] = f2bf(carry);
    carry = P*carry + he;
  }
}

// phase 3: re-scan chunk from true h_start, emit z = y + x*Dskip (bf16)
__global__ __launch_bounds__(256) void scan_p3(
    const u16* __restrict__ delta, const u16* __restrict__ xn3,
    const float* __restrict__ BI, const float* __restrict__ CI,
    const float* __restrict__ A_log, const float* __restrict__ x,
    const float* __restrict__ Dskip, const u16* __restrict__ hst,
    u16* __restrict__ z)
{
  __shared__ float ypart[4][TCH][64];
  const int tid = threadIdx.x;
  const int lane = tid & 63;
  const int wv = __builtin_amdgcn_readfirstlane(tid >> 6);
  const int dg = blockIdx.x, c = blockIdx.y, b = blockIdx.z;
  const int d = dg*64 + lane;
  const int nb = wv*16;
  float A2[16], h[16];
  #pragma unroll
  for (int n0=0;n0<4;++n0){
    float4 al = *(const float4*)(A_log + (size_t)d*64 + nb + n0*4);
    A2[n0*4+0] = -__expf(al.x)*LOG2E;
    A2[n0*4+1] = -__expf(al.y)*LOG2E;
    A2[n0*4+2] = -__expf(al.z)*LOG2E;
    A2[n0*4+3] = -__expf(al.w)*LOG2E;
  }
  #pragma unroll
  for (int n=0;n<16;++n)
    h[n] = bf2f(hst[(size_t)((c*2+b)*64 + nb + n)*1024 + d]);
  const int row0 = b*1024 + c*TCH;
  for (int t=0;t<TCH;++t){
    const size_t row = row0 + t;
    float dt = bf2f(delta[row*1024 + d]);
    float xt = bf2f(xn3[row*1024 + d]);
    float k = dt*xt;
    const float* bi = BI + row*64 + nb;
    const float* ci = CI + row*64 + nb;
    float y0=0.f, y1=0.f, y2=0.f, y3=0.f;
    #pragma unroll
    for (int n=0;n<16;n+=4){
      h[n+0] = fexp2(dt*A2[n+0])*h[n+0] + k*bi[n+0];  y0 += h[n+0]*ci[n+0];
      h[n+1] = fexp2(dt*A2[n+1])*h[n+1] + k*bi[n+1];  y1 += h[n+1]*ci[n+1];
      h[n+2] = fexp2(dt*A2[n+2])*h[n+2] + k*bi[n+2];  y2 += h[n+2]*ci[n+2];
      h[n+3] = fexp2(dt*A2[n+3])*h[n+3] + k*bi[n+3];  y3 += h[n+3]*ci[n+3];
    }
    ypart[wv][t][lane] = (y0+y1)+(y2+y3);
  }
  __syncthreads();
  const int dbase = dg*64;
  #pragma unroll
  for (int i=0;i<8;++i){
    int idx = tid + i*256;
    int t = idx>>6, dl = idx&63;
    size_t row = row0 + t;
    float y = ypart[0][t][dl] + ypart[1][t][dl] + ypart[2][t][dl] + ypart[3][t][dl];
    float xr = x[row*1024 + dbase + dl];
    z[row*1024 + dbase + dl] = f2bf(y + xr*Dskip[dbase+dl]);
  }
}

// ---------------- launch ----------------
extern "C" void kernel_launch(void* const* d_in, const int* in_sizes, int n_in,
                              void* d_out, int out_size, void* d_ws, size_t ws_size,
                              hipStream_t stream) {
  const float* x       = (const float*)d_in[0];
  const float* norm_w  = (const float*)d_in[1];
  const float* Wx      = (const float*)d_in[2];
  const float* dtW     = (const float*)d_in[3];
  const float* dtb     = (const float*)d_in[4];
  const float* A_log   = (const float*)d_in[5];
  const float* Dskip   = (const float*)d_in[6];
  const float* Wout    = (const float*)d_in[7];
  const float* selW    = (const float*)d_in[8];
  const float* selb    = (const float*)d_in[9];
  const float* sel_gate= (const float*)d_in[10];
  const float* impW    = (const float*)d_in[11];
  const float* impb    = (const float*)d_in[12];
  const float* gateW   = (const float*)d_in[13];
  const float* gateb   = (const float*)d_in[14];
  float* out = (float*)d_out;

  char* w = (char*)d_ws;
  u16*  wsA   = (u16*)(w);                       // 1216x1024 bf16 : [selW | Wx]
  u16*  wsB   = (u16*)(w + 2490368);             // 1088x1024 bf16 : [gateW | impW]
  u16*  wsC   = (u16*)(w + 4718592);             // 1024x1024 bf16 : Wout
  u16*  wsD   = (u16*)(w + 6815744);             // 1024x64 bf16 : dtW
  u16*  xn    = (u16*)(w + 6946816);             // 2048x1024 bf16
  u16*  xn2   = (u16*)(w + 11141120);            // 2048x1024 bf16
  u16*  hst   = (u16*)(w + 6946816);             // 64x64x1024 bf16 = 8.39MB (aliases xn/xn2, used after MODE1)
  u16*  dr    = (u16*)(w + 15335424);            // 2048x64 bf16 : delta_r
  u16*  delta16=(u16*)(w + 15597568);            // 2048x1024 bf16
  u16*  xn316 = (u16*)(w + 19791872);            // 2048x1024 bf16
  float* BCb  = (float*)(w + 23986176);          // 2048x128 f32 (dead after MODE1)
  float* sdt  = (float*)(w + 23986176);          // 64x1024 f32 (aliases BCb; written by p1)
  float* BIp  = (float*)(w + 25034752);          // 2048x64 f32
  float* CIp  = (float*)(w + 25559040);          // 2048x64 f32
  u16*  zb    = (u16*)(w + 26083328);            // 2048x1024 bf16 (end 30277632)

  convert_k<<<3393, 256, 0, stream>>>(selW, Wx, gateW, impW, Wout, dtW,
                                      wsA, wsB, wsC, wsD);
  rmsnorm_k<<<2048, 256, 0, stream>>>(x, norm_w, xn);
  gemm_bt<0><<<dim3(19,32), 256, 0, stream>>>(xn, wsA, selb, sel_gate, nullptr, xn,
                                              xn2, dr, nullptr, BCb, nullptr);
  delta_k<<<dim3(16,32), 256, 0, stream>>>(dr, wsD, dtb, delta16);
  gemm_bt<1><<<dim3(17,32), 256, 0, stream>>>(xn2, wsB, gateb, impb, BCb, xn2,
                                              xn316, nullptr, nullptr, BIp, CIp);
  scan_p1<<<dim3(16,NCHUNK,2), 256, 0, stream>>>(delta16, xn316, BIp, A_log, hst, sdt);
  scan_p2<<<512, 256, 0, stream>>>(A_log, sdt, hst);
  scan_p3<<<dim3(16,NCHUNK,2), 256, 0, stream>>>(delta16, xn316, BIp, CIp, A_log, x, Dskip, hst, zb);
  gemm_bt<2><<<dim3(16,32), 256, 0, stream>>>(zb, wsC, nullptr, nullptr, nullptr, nullptr,
                                              nullptr, nullptr, out, nullptr, nullptr);
}

// Round 13
// 111.402 us; speedup vs baseline: 1.1950x; 1.1950x over previous
//
#include <hip/hip_runtime.h>

typedef __attribute__((ext_vector_type(8))) short short8;
typedef __attribute__((ext_vector_type(4))) float f32x4;
typedef unsigned short u16;

// ---------------- helpers ----------------
__device__ __forceinline__ u16 f2bf(float f){
  unsigned int u = __float_as_uint(f);
  u += 0x7FFFu + ((u>>16)&1u);
  return (u16)(u>>16);
}
__device__ __forceinline__ float bf2f(u16 h){
  return __uint_as_float(((unsigned int)h)<<16);
}
__device__ __forceinline__ float sigm(float x){ return 1.f/(1.f+__expf(-x)); }

// raw v_exp_f32 (base-2); exp2f() goes through OCML fixup code.
__device__ __forceinline__ float fexp2(float x){
#if __has_builtin(__builtin_amdgcn_exp2f)
  return __builtin_amdgcn_exp2f(x);
#else
  float r; asm("v_exp_f32 %0, %1" : "=v"(r) : "v"(x)); return r;
#endif
}

// async global->LDS, 16B per lane. LDS dest = wave-uniform base + lane*16.
__device__ __forceinline__ void gl_lds(const u16* g, u16* l){
  __builtin_amdgcn_global_load_lds(
      (const __attribute__((address_space(1))) void*)g,
      (__attribute__((address_space(3))) void*)l, 16, 0, 0);
}

#define MDIM 2048
#define DDIM 1024
#define KDIM 1024
#define LOG2E 1.44269504f
#define NCHUNK 32   // chunks per sequence
#define TCH 32      // timesteps per chunk
#define CVT_TOTAL 3473408   // selW 1048576 + Wx 196608 + gateW 1048576 + impW 65536 + Wout 1048576 + dtW 65536

// ---------------- pre_k: rmsnorm (blocks 0..2047) + weight f32->bf16 convert ----------------
__global__ __launch_bounds__(256) void pre_k(
    const float* __restrict__ x, const float* __restrict__ nw,
    const float* __restrict__ selW, const float* __restrict__ Wx,
    const float* __restrict__ gateW, const float* __restrict__ impW,
    const float* __restrict__ Wout, const float* __restrict__ dtW,
    u16* __restrict__ xn,
    u16* __restrict__ dA, u16* __restrict__ dB, u16* __restrict__ dC,
    u16* __restrict__ dD)
{
  const int bx = blockIdx.x, tid = threadIdx.x;
  if (bx < 2048){
    // ---- rmsnorm row ----
    float4 xv = ((const float4*)(x + (size_t)bx*DDIM))[tid];
    float s = xv.x*xv.x + xv.y*xv.y + xv.z*xv.z + xv.w*xv.w;
    #pragma unroll
    for (int m=1; m<64; m<<=1) s += __shfl_xor(s, m);
    __shared__ float red[4];
    if ((tid&63)==0) red[tid>>6] = s;
    __syncthreads();
    float tot = red[0]+red[1]+red[2]+red[3];
    float rs = rsqrtf(tot*(1.f/1024.f) + 1e-6f);
    float4 wv = ((const float4*)nw)[tid];
    ushort4 o;
    o.x=f2bf(xv.x*rs*wv.x); o.y=f2bf(xv.y*rs*wv.y);
    o.z=f2bf(xv.z*rs*wv.z); o.w=f2bf(xv.w*rs*wv.w);
    ((ushort4*)(xn + (size_t)bx*DDIM))[tid] = o;
  } else {
    // ---- weight convert ----
    int e = ((bx-2048)*256 + tid)*4;
    if (e >= CVT_TOTAL) return;   // FIXED: was 3473664 -> OOB write into xn[0..255]
    const float4* s; u16* d;
    if (e < 1048576){ s=(const float4*)(selW+e); d=dA+e; }
    else if (e < 1245184){ int o=e-1048576; s=(const float4*)(Wx+o); d=dA+1048576+o; }
    else if (e < 2293760){ int o=e-1245184; s=(const float4*)(gateW+o); d=dB+o; }
    else if (e < 2359296){ int o=e-2293760; s=(const float4*)(impW+o); d=dB+1048576+o; }
    else if (e < 3407872){ int o=e-2359296; s=(const float4*)(Wout+o); d=dC+o; }
    else { int o=e-3407872; s=(const float4*)(dtW+o); d=dD+o; }
    float4 v = *s;
    ushort4 ov; ov.x=f2bf(v.x); ov.y=f2bf(v.y); ov.z=f2bf(v.z); ov.w=f2bf(v.w);
    *(ushort4*)d = ov;
  }
}

// ---------------- MFMA GEMM: C[m,n] = sum_k X[m,k]*W[n,k], K=1024 ----------------
// Round-10 proven pipeline: tile 64x64, BK=64, dbuf + raw s_barrier + counted
// vmcnt(4). T2 source-pre-swizzle; T1 XCD swizzle (nwg%8==0).
// MODE 0: W=[selW|Wx] N=1216 -> xn2(bf16), delta_r(bf16), BC(f32)
// MODE 1: W=[gateW|impW] N=1088 -> xn3(bf16), BI=B*imp, CI=C*imp (f32)
// MODE 2: W=Wout N=1024 -> out(f32)
template<int MODE>
__device__ __forceinline__ void gemm_body(
    u16* smem,   // 32KB pool: As0|As1|Bs0|Bs1, 4096 u16 each
    const u16* __restrict__ X, const u16* __restrict__ W,
    const float* __restrict__ b1, const float* __restrict__ b2,
    const float* __restrict__ b3, const u16* __restrict__ aux,
    u16* __restrict__ oBF, u16* __restrict__ oBF2,
    float* __restrict__ oF1, float* __restrict__ oF2, float* __restrict__ oF3)
{
  u16* const AsP[2] = { smem, smem + 4096 };
  u16* const BsP[2] = { smem + 8192, smem + 12288 };
  const int tid = threadIdx.x;
  const int wid = tid>>6, lane = tid&63;
  const int wr = wid>>1, wc = wid&1;
  const int lr = lane&15, lg = lane>>4;

  // T1: XCD-contiguous logical tiles
  const int nx = gridDim.x;
  const int nwg = nx*gridDim.y;
  const int lin = blockIdx.y*nx + blockIdx.x;
  const int lt = (lin&7)*(nwg>>3) + (lin>>3);
  const int bm = (lt/nx)*64, bn = (lt%nx)*64;

  f32x4 acc[2][2];
  #pragma unroll
  for (int a0=0;a0<2;++a0)
    #pragma unroll
    for (int b0=0;b0<2;++b0) acc[a0][b0] = (f32x4){0.f,0.f,0.f,0.f};

  // staging map (T2 pre-swizzled source k-slot, linear LDS dest)
  const int srow = wid*8 + (lane>>3);
  const int kslot = 8*((lane&7) ^ (lane>>3));   // u16 units
  const u16* ag = X + (size_t)(bm + srow)*KDIM + kslot;
  const u16* bg = W + (size_t)(bn + srow)*KDIM + kslot;
  const int lofs = wid*512;                      // u16

  // 4 gl_lds per wave per tile -> vmcnt(4) == "my previous tile has landed"
  auto stage = [&](int buf, int kt){
    gl_lds(ag + kt, AsP[buf] + lofs);
    gl_lds(ag + (size_t)32*KDIM + kt, AsP[buf] + 2048 + lofs);
    gl_lds(bg + kt, BsP[buf] + lofs);
    gl_lds(bg + (size_t)32*KDIM + kt, BsP[buf] + 2048 + lofs);
  };

  stage(0, 0);
  stage(1, 64);
  asm volatile("s_waitcnt vmcnt(4)" ::: "memory");
  __builtin_amdgcn_s_barrier();

  int cur = 0;
  #pragma unroll
  for (int kt=0; kt<KDIM; kt+=64){
    short8 af[2][2], bfr[2][2];
    #pragma unroll
    for (int a0=0;a0<2;++a0){
      const int R = wr*32 + a0*16 + lr;
      #pragma unroll
      for (int kh=0;kh<2;++kh)
        af[a0][kh] = *(const short8*)(AsP[cur] + R*64 + ((kh*32 + lg*8) ^ ((lr&7)<<3)));
    }
    #pragma unroll
    for (int b0=0;b0<2;++b0){
      const int R = wc*32 + b0*16 + lr;
      #pragma unroll
      for (int kh=0;kh<2;++kh)
        bfr[b0][kh] = *(const short8*)(BsP[cur] + R*64 + ((kh*32 + lg*8) ^ ((lr&7)<<3)));
    }
    asm volatile("s_waitcnt lgkmcnt(0)" ::: "memory");
    __builtin_amdgcn_sched_barrier(0);
    __builtin_amdgcn_s_barrier();
    if (kt < KDIM-128)
      stage(cur, kt+128);            // overwrite buf[cur] with tile k+2
    #pragma unroll
    for (int kh=0;kh<2;++kh)
      #pragma unroll
      for (int a0=0;a0<2;++a0)
        #pragma unroll
        for (int b0=0;b0<2;++b0)
          acc[a0][b0] = __builtin_amdgcn_mfma_f32_16x16x32_bf16(af[a0][kh], bfr[b0][kh], acc[a0][b0], 0, 0, 0);
    __builtin_amdgcn_sched_barrier(0); // keep MFMA above the wait
    if (kt < KDIM-128){
      asm volatile("s_waitcnt vmcnt(4)" ::: "memory");
      __builtin_amdgcn_s_barrier();
    } else if (kt < KDIM-64){
      asm volatile("s_waitcnt vmcnt(0)" ::: "memory");
      __builtin_amdgcn_s_barrier();
    }
    cur ^= 1;
  }

  const int colb = bn + wc*32;
  #pragma unroll
  for (int a0=0;a0<2;++a0){
    const int m0 = bm + wr*32 + a0*16 + lg*4;
    #pragma unroll
    for (int b0=0;b0<2;++b0){
      const int n = colb + b0*16 + lr;
      #pragma unroll
      for (int i=0;i<4;++i){
        const int m = m0 + i;
        float v = acc[a0][b0][i];
        if constexpr (MODE==0){
          if (n < 1024){
            float s = sigm((v + b1[n])*b2[n]);
            float xnv = bf2f(aux[(size_t)m*1024 + n]);
            oBF[(size_t)m*1024 + n] = f2bf(xnv*s);
          } else if (n < 1088){
            oBF2[(size_t)m*64 + (n-1024)] = f2bf(v);        // delta_r
          } else {
            oF2[(size_t)m*128 + (n-1088)] = v;              // B,C
          }
        } else if constexpr (MODE==1){
          if (n < 1024){
            float g = sigm(v + b1[n]);
            oBF[(size_t)m*1024 + n] = f2bf(bf2f(aux[(size_t)m*1024 + n])*g);  // xn3 bf16
          } else {
            int c = n-1024;
            float it = sigm(v + b2[c]);
            float bb = b3[(size_t)m*128 + c];
            float cc = b3[(size_t)m*128 + 64 + c];
            oF2[(size_t)m*64 + c] = bb*it;   // BI = B*imp
            oF3[(size_t)m*64 + c] = cc*it;   // CI = C*imp
          }
        } else {
          oF1[(size_t)m*1024 + n] = v;
        }
      }
    }
  }
}

template<int MODE>
__global__ __launch_bounds__(256) void gemm_bt(
    const u16* __restrict__ X, const u16* __restrict__ W,
    const float* __restrict__ b1, const float* __restrict__ b2,
    const float* __restrict__ b3, const u16* __restrict__ aux,
    u16* __restrict__ oBF, u16* __restrict__ oBF2,
    float* __restrict__ oF1, float* __restrict__ oF2, float* __restrict__ oF3)
{
  __shared__ __align__(16) u16 pool[16384];
  gemm_body<MODE>(pool, X, W, b1, b2, b3, aux, oBF, oBF2, oF1, oF2, oF3);
}

// ---------------- gemm1d_k: z=0 -> gemm MODE1; z=1 -> delta_k ----------------
// delta[m,d] = softplus(sum_r dr[m,r]*dtW[d,r] + dtb[d]); K=64 one-shot MFMA.
__global__ __launch_bounds__(256) void gemm1d_k(
    const u16* __restrict__ xn2, const u16* __restrict__ wsB,
    const float* __restrict__ gateb, const float* __restrict__ impb,
    const float* __restrict__ BCb,
    u16* __restrict__ xn316, float* __restrict__ BIp, float* __restrict__ CIp,
    const u16* __restrict__ dr, const u16* __restrict__ dtWb,
    const float* __restrict__ dtb, u16* __restrict__ delta16)
{
  __shared__ __align__(16) u16 pool[16384];
  if (blockIdx.z == 0){
    gemm_body<1>(pool, xn2, wsB, gateb, impb, BCb, xn2,
                 xn316, nullptr, nullptr, BIp, CIp);
    return;
  }
  // ---- delta path (needs only 16x32 of the 17x32 grid) ----
  if (blockIdx.x >= 16) return;
  u16* As = pool;           // 64x64
  u16* Bs = pool + 4096;
  const int tid = threadIdx.x;
  const int wid = tid>>6, lane = tid&63;
  const int wr = wid>>1, wc = wid&1;
  const int lr = lane&15, lg = lane>>4;
  const int bm = blockIdx.y*64, bn = blockIdx.x*64;

  const int srow = wid*8 + (lane>>3);
  const int kslot = 8*((lane&7) ^ (lane>>3));
  const u16* ag = dr   + (size_t)(bm + srow)*64 + kslot;
  const u16* bg = dtWb + (size_t)(bn + srow)*64 + kslot;
  const int lofs = wid*512;

  gl_lds(ag, As + lofs);
  gl_lds(ag + 32*64, As + 2048 + lofs);
  gl_lds(bg, Bs + lofs);
  gl_lds(bg + 32*64, Bs + 2048 + lofs);
  asm volatile("s_waitcnt vmcnt(0)" ::: "memory");
  __builtin_amdgcn_s_barrier();

  f32x4 acc[2][2];
  #pragma unroll
  for (int a0=0;a0<2;++a0)
    #pragma unroll
    for (int b0=0;b0<2;++b0) acc[a0][b0] = (f32x4){0.f,0.f,0.f,0.f};

  short8 af[2][2], bfr[2][2];
  #pragma unroll
  for (int a0=0;a0<2;++a0){
    const int R = wr*32 + a0*16 + lr;
    #pragma unroll
    for (int kh=0;kh<2;++kh)
      af[a0][kh] = *(const short8*)(As + R*64 + ((kh*32 + lg*8) ^ ((lr&7)<<3)));
  }
  #pragma unroll
  for (int b0=0;b0<2;++b0){
    const int R = wc*32 + b0*16 + lr;
    #pragma unroll
    for (int kh=0;kh<2;++kh)
      bfr[b0][kh] = *(const short8*)(Bs + R*64 + ((kh*32 + lg*8) ^ ((lr&7)<<3)));
  }
  #pragma unroll
  for (int kh=0;kh<2;++kh)
    #pragma unroll
    for (int a0=0;a0<2;++a0)
      #pragma unroll
      for (int b0=0;b0<2;++b0)
        acc[a0][b0] = __builtin_amdgcn_mfma_f32_16x16x32_bf16(af[a0][kh], bfr[b0][kh], acc[a0][b0], 0, 0, 0);

  #pragma unroll
  for (int a0=0;a0<2;++a0){
    const int m0 = bm + wr*32 + a0*16 + lg*4;
    #pragma unroll
    for (int b0=0;b0<2;++b0){
      const int n = bn + wc*32 + b0*16 + lr;
      const float bias = dtb[n];
      #pragma unroll
      for (int i=0;i<4;++i){
        float t = acc[a0][b0][i] + bias;
        float sp = fmaxf(t,0.f) + log1pf(__expf(-fabsf(t)));
        delta16[(size_t)(m0+i)*1024 + n] = f2bf(sp);
      }
    }
  }
}

// ---------------- chunked selective scan (bf16 delta/xn3 inputs) ----------------
// 32 chunks x 32 steps; block = 256 threads = 4 waves; wave wv owns n-states
// [wv*16, wv*16+16); lane = d. hst is bf16: [c*2+b][n][d].
__global__ __launch_bounds__(256) void scan_p1(
    const u16* __restrict__ delta, const u16* __restrict__ xn3,
    const float* __restrict__ BI, const float* __restrict__ A_log,
    u16* __restrict__ hst, float* __restrict__ sumdt)
{
  const int tid = threadIdx.x;
  const int lane = tid & 63;
  const int wv = __builtin_amdgcn_readfirstlane(tid >> 6);
  const int dg = blockIdx.x, c = blockIdx.y, b = blockIdx.z;
  const int d = dg*64 + lane;
  const int nb = wv*16;
  float A2[16], h[16];
  #pragma unroll
  for (int n0=0;n0<4;++n0){
    float4 al = *(const float4*)(A_log + (size_t)d*64 + nb + n0*4);
    A2[n0*4+0] = -__expf(al.x)*LOG2E;
    A2[n0*4+1] = -__expf(al.y)*LOG2E;
    A2[n0*4+2] = -__expf(al.z)*LOG2E;
    A2[n0*4+3] = -__expf(al.w)*LOG2E;
  }
  #pragma unroll
  for (int n=0;n<16;++n) h[n]=0.f;
  const int row0 = b*1024 + c*TCH;
  float sdt = 0.f;
  for (int t=0;t<TCH;++t){
    const size_t row = row0 + t;
    float dt = bf2f(delta[row*1024 + d]);
    float xt = bf2f(xn3[row*1024 + d]);
    sdt += dt;
    float k = dt*xt;
    const float* bi = BI + row*64 + nb;   // wave-uniform -> s_loads
    #pragma unroll
    for (int n=0;n<16;++n)
      h[n] = fexp2(dt*A2[n])*h[n] + k*bi[n];
  }
  if (wv==0) sumdt[(size_t)(c*2+b)*1024 + d] = sdt;
  #pragma unroll
  for (int n=0;n<16;++n)
    hst[(size_t)((c*2+b)*64 + nb + n)*1024 + d] = f2bf(h[n]);
}

// phase 2: sequential prefix over 32 chunks, in-place: hst[c] <- h_start of chunk c
__global__ __launch_bounds__(256) void scan_p2(
    const float* __restrict__ A_log, const float* __restrict__ sumdt,
    u16* __restrict__ hst)
{
  int gid = blockIdx.x*256 + threadIdx.x;   // 512 blocks -> 131072 threads
  int d = gid & 1023, n = (gid>>10)&63, b = gid>>16;
  float A2 = -__expf(A_log[(size_t)d*64 + n])*LOG2E;
  float carry = 0.f;
  #pragma unroll
  for (int c=0;c<NCHUNK;++c){
    float P = fexp2(A2 * sumdt[(size_t)(c*2+b)*1024 + d]);
    size_t off = (size_t)((c*2+b)*64 + n)*1024 + d;
    float he = bf2f(hst[off]);
    hst[off] = f2bf(carry);
    carry = P*carry + he;
  }
}

// phase 3: re-scan chunk from true h_start, emit z = y + x*Dskip (bf16)
__global__ __launch_bounds__(256) void scan_p3(
    const u16* __restrict__ delta, const u16* __restrict__ xn3,
    const float* __restrict__ BI, const float* __restrict__ CI,
    const float* __restrict__ A_log, const float* __restrict__ x,
    const float* __restrict__ Dskip, const u16* __restrict__ hst,
    u16* __restrict__ z)
{
  __shared__ float ypart[4][TCH][64];
  const int tid = threadIdx.x;
  const int lane = tid & 63;
  const int wv = __builtin_amdgcn_readfirstlane(tid >> 6);
  const int dg = blockIdx.x, c = blockIdx.y, b = blockIdx.z;
  const int d = dg*64 + lane;
  const int nb = wv*16;
  float A2[16], h[16];
  #pragma unroll
  for (int n0=0;n0<4;++n0){
    float4 al = *(const float4*)(A_log + (size_t)d*64 + nb + n0*4);
    A2[n0*4+0] = -__expf(al.x)*LOG2E;
    A2[n0*4+1] = -__expf(al.y)*LOG2E;
    A2[n0*4+2] = -__expf(al.z)*LOG2E;
    A2[n0*4+3] = -__expf(al.w)*LOG2E;
  }
  #pragma unroll
  for (int n=0;n<16;++n)
    h[n] = bf2f(hst[(size_t)((c*2+b)*64 + nb + n)*1024 + d]);
  const int row0 = b*1024 + c*TCH;
  for (int t=0;t<TCH;++t){
    const size_t row = row0 + t;
    float dt = bf2f(delta[row*1024 + d]);
    float xt = bf2f(xn3[row*1024 + d]);
    float k = dt*xt;
    const float* bi = BI + row*64 + nb;
    const float* ci = CI + row*64 + nb;
    float y0=0.f, y1=0.f, y2=0.f, y3=0.f;
    #pragma unroll
    for (int n=0;n<16;n+=4){
      h[n+0] = fexp2(dt*A2[n+0])*h[n+0] + k*bi[n+0];  y0 += h[n+0]*ci[n+0];
      h[n+1] = fexp2(dt*A2[n+1])*h[n+1] + k*bi[n+1];  y1 += h[n+1]*ci[n+1];
      h[n+2] = fexp2(dt*A2[n+2])*h[n+2] + k*bi[n+2];  y2 += h[n+2]*ci[n+2];
      h[n+3] = fexp2(dt*A2[n+3])*h[n+3] + k*bi[n+3];  y3 += h[n+3]*ci[n+3];
    }
    ypart[wv][t][lane] = (y0+y1)+(y2+y3);
  }
  __syncthreads();
  const int dbase = dg*64;
  #pragma unroll
  for (int i=0;i<8;++i){
    int idx = tid + i*256;
    int t = idx>>6, dl = idx&63;
    size_t row = row0 + t;
    float y = ypart[0][t][dl] + ypart[1][t][dl] + ypart[2][t][dl] + ypart[3][t][dl];
    float xr = x[row*1024 + dbase + dl];
    z[row*1024 + dbase + dl] = f2bf(y + xr*Dskip[dbase+dl]);
  }
}

// ---------------- launch ----------------
extern "C" void kernel_launch(void* const* d_in, const int* in_sizes, int n_in,
                              void* d_out, int out_size, void* d_ws, size_t ws_size,
                              hipStream_t stream) {
  const float* x       = (const float*)d_in[0];
  const float* norm_w  = (const float*)d_in[1];
  const float* Wx      = (const float*)d_in[2];
  const float* dtW     = (const float*)d_in[3];
  const float* dtb     = (const float*)d_in[4];
  const float* A_log   = (const float*)d_in[5];
  const float* Dskip   = (const float*)d_in[6];
  const float* Wout    = (const float*)d_in[7];
  const float* selW    = (const float*)d_in[8];
  const float* selb    = (const float*)d_in[9];
  const float* sel_gate= (const float*)d_in[10];
  const float* impW    = (const float*)d_in[11];
  const float* impb    = (const float*)d_in[12];
  const float* gateW   = (const float*)d_in[13];
  const float* gateb   = (const float*)d_in[14];
  float* out = (float*)d_out;

  char* w = (char*)d_ws;
  u16*  wsA   = (u16*)(w);                       // 1216x1024 bf16 : [selW | Wx]
  u16*  wsB   = (u16*)(w + 2490368);             // 1088x1024 bf16 : [gateW | impW]
  u16*  wsC   = (u16*)(w + 4718592);             // 1024x1024 bf16 : Wout
  u16*  wsD   = (u16*)(w + 6815744);             // 1024x64 bf16 : dtW
  u16*  xn    = (u16*)(w + 6946816);             // 2048x1024 bf16
  u16*  xn2   = (u16*)(w + 11141120);            // 2048x1024 bf16
  u16*  hst   = (u16*)(w + 6946816);             // 64x64x1024 bf16 = 8.39MB (aliases xn/xn2, used after MODE1)
  u16*  dr    = (u16*)(w + 15335424);            // 2048x64 bf16 : delta_r
  u16*  delta16=(u16*)(w + 15597568);            // 2048x1024 bf16
  u16*  xn316 = (u16*)(w + 19791872);            // 2048x1024 bf16
  float* BCb  = (float*)(w + 23986176);          // 2048x128 f32 (dead after MODE1)
  float* sdt  = (float*)(w + 23986176);          // 64x1024 f32 (aliases BCb; written by p1)
  float* BIp  = (float*)(w + 25034752);          // 2048x64 f32
  float* CIp  = (float*)(w + 25559040);          // 2048x64 f32
  u16*  zb    = (u16*)(w + 26083328);            // 2048x1024 bf16 (end 30277632)

  pre_k<<<2048+3392, 256, 0, stream>>>(x, norm_w, selW, Wx, gateW, impW, Wout, dtW,
                                       xn, wsA, wsB, wsC, wsD);
  gemm_bt<0><<<dim3(19,32), 256, 0, stream>>>(xn, wsA, selb, sel_gate, nullptr, xn,
                                              xn2, dr, nullptr, BCb, nullptr);
  gemm1d_k<<<dim3(17,32,2), 256, 0, stream>>>(xn2, wsB, gateb, impb, BCb,
                                              xn316, BIp, CIp,
                                              dr, wsD, dtb, delta16);
  scan_p1<<<dim3(16,NCHUNK,2), 256, 0, stream>>>(delta16, xn316, BIp, A_log, hst, sdt);
  scan_p2<<<512, 256, 0, stream>>>(A_log, sdt, hst);
  scan_p3<<<dim3(16,NCHUNK,2), 256, 0, stream>>>(delta16, xn316, BIp, CIp, A_log, x, Dskip, hst, zb);
  gemm_bt<2><<<dim3(16,32), 256, 0, stream>>>(zb, wsC, nullptr, nullptr, nullptr, nullptr,
                                              nullptr, nullptr, out, nullptr, nullptr);
}